// Round 8
// baseline (521.218 us; speedup 1.0000x reference)
//
#include <hip/hip_runtime.h>
#include <stdint.h>

typedef __attribute__((ext_vector_type(8))) short short8;
typedef __attribute__((ext_vector_type(4))) float f32x4;
typedef __attribute__((ext_vector_type(4))) unsigned short u16x4;

typedef unsigned short u16;

constexpr int S_LEN = 2048;
constexpr int DH    = 128;

__device__ __forceinline__ u16 f2bf(float f) {
    union { float f; unsigned u; } v; v.f = f;
    unsigned r = v.u + 0x7FFFu + ((v.u >> 16) & 1u);
    return (u16)(r >> 16);
}
__device__ __forceinline__ void gl_lds16(const void* g, void* l) {
    __builtin_amdgcn_global_load_lds((const __attribute__((address_space(1))) void*)g,
                                     (__attribute__((address_space(3))) void*)l,
                                     16, 0, 0);
}

// ---------- fp32 -> bf16 bulk convert ----------
__global__ __launch_bounds__(256) void convx(const float* __restrict__ src,
                                             u16* __restrict__ dst) {
    size_t i = ((size_t)blockIdx.x * 256 + threadIdx.x) * 8;
    f32x4 a = *(const f32x4*)(src + i);
    f32x4 b = *(const f32x4*)(src + i + 4);
    short8 r;
    r[0] = (short)f2bf(a[0]); r[1] = (short)f2bf(a[1]);
    r[2] = (short)f2bf(a[2]); r[3] = (short)f2bf(a[3]);
    r[4] = (short)f2bf(b[0]); r[5] = (short)f2bf(b[1]);
    r[6] = (short)f2bf(b[2]); r[7] = (short)f2bf(b[3]);
    *(short8*)(dst + i) = r;
}

// ---------- fp32 [rows][cols] -> bf16 transposed [cols][rows] ----------
__global__ void convT(const float* __restrict__ src, u16* __restrict__ dst,
                      int rows, int cols) {
    __shared__ u16 tile[32][33];
    int c0 = blockIdx.x * 32, r0 = blockIdx.y * 32;
    int tx = threadIdx.x, ty = threadIdx.y;
#pragma unroll
    for (int i = 0; i < 32; i += 8)
        tile[ty + i][tx] = f2bf(src[(size_t)(r0 + ty + i) * cols + c0 + tx]);
    __syncthreads();
#pragma unroll
    for (int i = 0; i < 32; i += 8)
        dst[(size_t)(c0 + ty + i) * rows + r0 + tx] = tile[tx][ty + i];
}

// ================= QKV GEMM (m97 structure) =================
__global__ __launch_bounds__(256) void gemm_qkv(
        const u16* __restrict__ A, const u16* __restrict__ BT,
        u16* __restrict__ Qo, u16* __restrict__ Ko, u16* __restrict__ VTo) {
    __shared__ __align__(16) u16 lA[128 * 32];
    __shared__ __align__(16) u16 lB[128 * 32];
    const int tid = threadIdx.x;
    const int lane = tid & 63, wave = tid >> 6;
    const int quad = lane >> 4, l16 = lane & 15;
    const int wm = wave >> 1, wn = wave & 1;
    const int m0 = blockIdx.y * 128, n0 = blockIdx.x * 128;
    f32x4 acc[4][4] = {};
    const int rbase = tid >> 2;
    const int cofs  = (tid & 3) * 8;

    for (int k0 = 0; k0 < 2048; k0 += 32) {
#pragma unroll
        for (int it = 0; it < 2; ++it) {
            int row = it * 64 + rbase;
            gl_lds16(A  + (size_t)(m0 + row) * 2048 + k0 + cofs, &lA[(it * 256 + tid) * 8]);
            gl_lds16(BT + (size_t)(n0 + row) * 2048 + k0 + cofs, &lB[(it * 256 + tid) * 8]);
        }
        __syncthreads();
        short8 af[4], bf[4];
#pragma unroll
        for (int i = 0; i < 4; ++i) {
            af[i] = *(const short8*)&lA[(wm * 64 + i * 16 + l16) * 32 + quad * 8];
            bf[i] = *(const short8*)&lB[(wn * 64 + i * 16 + l16) * 32 + quad * 8];
        }
#pragma unroll
        for (int im = 0; im < 4; ++im)
#pragma unroll
            for (int in = 0; in < 4; ++in)
                acc[im][in] = __builtin_amdgcn_mfma_f32_16x16x32_bf16(af[im], bf[in], acc[im][in], 0, 0, 0);
        __syncthreads();
    }
#pragma unroll
    for (int im = 0; im < 4; ++im) {
        int r0r = m0 + wm * 64 + im * 16 + quad * 4;
        int b = r0r >> 11, s0 = r0r & 2047;
#pragma unroll
        for (int in = 0; in < 4; ++in) {
            int cc = n0 + wn * 64 + in * 16 + l16;
            int which = cc >> 11, hd = (cc >> 7) & 15, dh = cc & 127;
            if (which < 2) {
                u16* dst = which == 0 ? Qo : Ko;
#pragma unroll
                for (int rg = 0; rg < 4; ++rg)
                    dst[(size_t)((b * 16 + hd) * 2048 + s0 + rg) * 128 + dh] = f2bf(acc[im][in][rg]);
            } else {
                u16x4 v;
#pragma unroll
                for (int rg = 0; rg < 4; ++rg) v[rg] = f2bf(acc[im][in][rg]);
                *(u16x4*)&VTo[((size_t)(b * 16 + hd) * 128 + dh) * 2048 + s0] = v;
            }
        }
    }
}

// ================= flash attention (causal, 128-q tile, 2 blocks/CU) ========
// grid (16,32); qt = 15-blockIdx.x (128 q-rows per block, long blocks first).
// block 256 = 4 waves; wave w owns 32 q-rows (2 m-tiles of 16).
// K natural [BH][S][DH]; VT [BH][DH][S]; O overwrites Q in place.
// Single-buffer K/V staging + register prefetch (2 barriers/iter).
// LDS: K 64x136 (17.4K) + V 128x72 (18.4K) + P 4x32x72 (18.4K) = 54.3 KB.
constexpr int KST = 136;   // K LDS row stride (u16), 272B = 17x16B
constexpr int VST = 72;    // VT LDS row stride (u16), 144B = 9x16B
constexpr int PST = 72;    // P LDS row stride (u16)

__global__ __launch_bounds__(256) void attn_kern(
        u16* __restrict__ QOp, const u16* __restrict__ Kp,
        const u16* __restrict__ VTp) {
    __shared__ __align__(16) u16 lK[64 * KST];
    __shared__ __align__(16) u16 lV[128 * VST];
    __shared__ __align__(16) u16 Pl[4][32 * PST];
    const int tid = threadIdx.x, lane = tid & 63, wave = tid >> 6;
    const int quad = lane >> 4, l16 = lane & 15;
    const int qt = 15 - blockIdx.x, bh = blockIdx.y;
    const int q0 = qt * 128 + wave * 32;   // wave's first q row
    u16* Qh = QOp + (size_t)bh * S_LEN * DH;
    const u16* Kh = Kp + (size_t)bh * S_LEN * DH;
    const u16* VTh = VTp + (size_t)bh * DH * S_LEN;
    u16* Pw = Pl[wave];

    const int krow = tid >> 4, kchunk = tid & 15;   // K: 16 rows/round x4
    const int vrow = tid >> 3, vchunk = tid & 7;    // V: 32 rows/round x4

    short8 aq[2][4];
#pragma unroll
    for (int m = 0; m < 2; ++m)
#pragma unroll
        for (int kk = 0; kk < 4; ++kk)
            aq[m][kk] = *(const short8*)&Qh[(size_t)(q0 + m * 16 + l16) * 128 + kk * 32 + quad * 8];

    f32x4 acc_o[2][8] = {};
    float m_i[2][4], l_i[2][4];
#pragma unroll
    for (int m = 0; m < 2; ++m)
#pragma unroll
        for (int r = 0; r < 4; ++r) { m_i[m][r] = -1e9f; l_i[m][r] = 0.f; }
    const float scale = 0.08838834764831845f;  // 1/sqrt(128)

    const int ktmax = 2 * qt + 1;
    short8 kr[4], vr[4];
#pragma unroll
    for (int r = 0; r < 4; ++r) {
        kr[r] = *(const short8*)&Kh[(size_t)(r * 16 + krow) * 128 + kchunk * 8];
        vr[r] = *(const short8*)&VTh[(size_t)(r * 32 + vrow) * 2048 + vchunk * 8];
    }

    for (int kt = 0; kt <= ktmax; ++kt) {
        // commit staged regs to LDS
#pragma unroll
        for (int r = 0; r < 4; ++r) {
            *(short8*)&lK[(r * 16 + krow) * KST + kchunk * 8] = kr[r];
            *(short8*)&lV[(r * 32 + vrow) * VST + vchunk * 8] = vr[r];
        }
        __syncthreads();
        if (kt < ktmax) {   // issue next tile's global loads (overlap compute)
            const size_t kb = (size_t)(kt + 1) * 64;
#pragma unroll
            for (int r = 0; r < 4; ++r) {
                kr[r] = *(const short8*)&Kh[(kb + r * 16 + krow) * 128 + kchunk * 8];
                vr[r] = *(const short8*)&VTh[(size_t)(r * 32 + vrow) * 2048 + kb + vchunk * 8];
            }
        }
        // QK^T: 16 LDS reads, 32 MFMA
        f32x4 sa[2][4] = {};
#pragma unroll
        for (int nt = 0; nt < 4; ++nt)
#pragma unroll
            for (int kk = 0; kk < 4; ++kk) {
                short8 bk = *(const short8*)&lK[(nt * 16 + l16) * KST + kk * 32 + quad * 8];
                sa[0][nt] = __builtin_amdgcn_mfma_f32_16x16x32_bf16(aq[0][kk], bk, sa[0][nt], 0, 0, 0);
                sa[1][nt] = __builtin_amdgcn_mfma_f32_16x16x32_bf16(aq[1][kk], bk, sa[1][nt], 0, 0, 0);
            }
        // online softmax per m-tile (2 independent chains)
#pragma unroll
        for (int m = 0; m < 2; ++m) {
            float sv[4][4];
            float mt[4] = {-1e9f, -1e9f, -1e9f, -1e9f};
#pragma unroll
            for (int nt = 0; nt < 4; ++nt) {
                int kg = kt * 64 + nt * 16 + l16;
#pragma unroll
                for (int rg = 0; rg < 4; ++rg) {
                    float s = sa[m][nt][rg] * scale;
                    int qg = q0 + m * 16 + quad * 4 + rg;
                    if (kg > qg) s = -1e9f;
                    sv[nt][rg] = s;
                    mt[rg] = fmaxf(mt[rg], s);
                }
            }
            float alpha[4];
#pragma unroll
            for (int rg = 0; rg < 4; ++rg) {
#pragma unroll
                for (int off = 8; off >= 1; off >>= 1)
                    mt[rg] = fmaxf(mt[rg], __shfl_xor(mt[rg], off));
                float mn = fmaxf(m_i[m][rg], mt[rg]);
                alpha[rg] = __expf(m_i[m][rg] - mn);
                m_i[m][rg] = mn;
                float rs = 0.f;
#pragma unroll
                for (int nt = 0; nt < 4; ++nt) {
                    float p = __expf(sv[nt][rg] - mn);
                    sv[nt][rg] = p;
                    rs += p;
                }
#pragma unroll
                for (int off = 8; off >= 1; off >>= 1)
                    rs += __shfl_xor(rs, off);
                l_i[m][rg] = l_i[m][rg] * alpha[rg] + rs;
            }
#pragma unroll
            for (int d = 0; d < 8; ++d)
#pragma unroll
                for (int rg = 0; rg < 4; ++rg)
                    acc_o[m][d][rg] *= alpha[rg];
            // P (C-layout) -> per-wave LDS (rows m*16 + quad*4+rg)
#pragma unroll
            for (int nt = 0; nt < 4; ++nt)
#pragma unroll
                for (int rg = 0; rg < 4; ++rg)
                    Pw[(m * 16 + quad * 4 + rg) * PST + nt * 16 + l16] = f2bf(sv[nt][rg]);
        }
        // P A-frags (same-wave RAW, no barrier needed)
        short8 ap[2][2];
#pragma unroll
        for (int m = 0; m < 2; ++m) {
            ap[m][0] = *(const short8*)&Pw[(m * 16 + l16) * PST + quad * 8];
            ap[m][1] = *(const short8*)&Pw[(m * 16 + l16) * PST + 32 + quad * 8];
        }
        // PV: 16 LDS reads, 32 MFMA
#pragma unroll
        for (int d = 0; d < 8; ++d) {
            short8 bv0 = *(const short8*)&lV[(d * 16 + l16) * VST + quad * 8];
            short8 bv1 = *(const short8*)&lV[(d * 16 + l16) * VST + 32 + quad * 8];
#pragma unroll
            for (int m = 0; m < 2; ++m) {
                acc_o[m][d] = __builtin_amdgcn_mfma_f32_16x16x32_bf16(ap[m][0], bv0, acc_o[m][d], 0, 0, 0);
                acc_o[m][d] = __builtin_amdgcn_mfma_f32_16x16x32_bf16(ap[m][1], bv1, acc_o[m][d], 0, 0, 0);
            }
        }
        __syncthreads();   // protect lK/lV before next commit
    }
#pragma unroll
    for (int m = 0; m < 2; ++m) {
        float rinv[4];
#pragma unroll
        for (int rg = 0; rg < 4; ++rg) rinv[rg] = 1.0f / l_i[m][rg];
#pragma unroll
        for (int d = 0; d < 8; ++d)
#pragma unroll
            for (int rg = 0; rg < 4; ++rg) {
                int s = q0 + m * 16 + quad * 4 + rg;
                Qh[(size_t)s * 128 + d * 16 + l16] = f2bf(acc_o[m][d][rg] * rinv[rg]);
            }
    }
}

// ================= proj GEMM (m97 structure, fp32 out) =================
__global__ __launch_bounds__(256) void gemm_proj(
        const u16* __restrict__ QO, const u16* __restrict__ BT,
        const float* __restrict__ bias, float* __restrict__ out) {
    __shared__ __align__(16) u16 lA[128 * 32];
    __shared__ __align__(16) u16 lB[128 * 32];
    const int tid = threadIdx.x;
    const int lane = tid & 63, wave = tid >> 6;
    const int quad = lane >> 4, l16 = lane & 15;
    const int wm = wave >> 1, wn = wave & 1;
    const int m0 = blockIdx.y * 128, n0 = blockIdx.x * 128;
    f32x4 acc[4][4] = {};
    const int rbase = tid >> 2;
    const int cofs  = (tid & 3) * 8;

    for (int k0 = 0; k0 < 2048; k0 += 32) {
#pragma unroll
        for (int it = 0; it < 2; ++it) {
            int row = m0 + it * 64 + rbase;
            int b = row >> 11, s = row & 2047;
            int k = k0 + cofs, h = k >> 7, dh = k & 127;
            gl_lds16(QO + ((size_t)(b * 16 + h) * 2048 + s) * 128 + dh, &lA[(it * 256 + tid) * 8]);
            gl_lds16(BT + (size_t)(n0 + it * 64 + rbase) * 2048 + k0 + cofs, &lB[(it * 256 + tid) * 8]);
        }
        __syncthreads();
        short8 af[4], bf[4];
#pragma unroll
        for (int i = 0; i < 4; ++i) {
            af[i] = *(const short8*)&lA[(wm * 64 + i * 16 + l16) * 32 + quad * 8];
            bf[i] = *(const short8*)&lB[(wn * 64 + i * 16 + l16) * 32 + quad * 8];
        }
#pragma unroll
        for (int im = 0; im < 4; ++im)
#pragma unroll
            for (int in = 0; in < 4; ++in)
                acc[im][in] = __builtin_amdgcn_mfma_f32_16x16x32_bf16(af[im], bf[in], acc[im][in], 0, 0, 0);
        __syncthreads();
    }
#pragma unroll
    for (int im = 0; im < 4; ++im) {
        int r0r = m0 + wm * 64 + im * 16 + quad * 4;
#pragma unroll
        for (int in = 0; in < 4; ++in) {
            int cc = n0 + wn * 64 + in * 16 + l16;
            float bv = bias[cc];
#pragma unroll
            for (int rg = 0; rg < 4; ++rg)
                out[(size_t)(r0r + rg) * 2048 + cc] = acc[im][in][rg] + bv;
        }
    }
}

extern "C" void kernel_launch(void* const* d_in, const int* in_sizes, int n_in,
                              void* d_out, int out_size, void* d_ws, size_t ws_size,
                              hipStream_t stream) {
    const float *x = nullptr, *Wqkv = nullptr, *Wproj = nullptr, *bproj = nullptr;
    for (int i = 0; i < n_in; ++i) {
        int sz = in_sizes[i];
        if      (sz == 2 * 2048 * 2048) x     = (const float*)d_in[i];
        else if (sz == 2048 * 6144)     Wqkv  = (const float*)d_in[i];
        else if (sz == 2048 * 2048)     Wproj = (const float*)d_in[i];
        else if (sz == 2048)            bproj = (const float*)d_in[i];
    }
    float* out = (float*)d_out;

    // ws overlay (92.3 MB peak, all bf16)
    u16* xb     = (u16*)d_ws;
    u16* WqkvT  = xb    + (size_t)4096 * 2048;
    u16* Qb     = WqkvT + (size_t)6144 * 2048;
    u16* Kb     = Qb    + (size_t)32 * 2048 * 128;
    u16* VTb    = Kb    + (size_t)32 * 2048 * 128;
    u16* WprojT = xb;   // overlay after xb dead

    convx<<<dim3(4096), dim3(256), 0, stream>>>(x, xb);
    convT<<<dim3(192, 64), dim3(32, 8), 0, stream>>>(Wqkv, WqkvT, 2048, 6144);
    gemm_qkv<<<dim3(48, 32), dim3(256), 0, stream>>>(xb, WqkvT, Qb, Kb, VTb);
    convT<<<dim3(64, 64), dim3(32, 8), 0, stream>>>(Wproj, WprojT, 2048, 2048);
    attn_kern<<<dim3(16, 32), dim3(256), 0, stream>>>(Qb, Kb, VTb);
    gemm_proj<<<dim3(16, 32), dim3(256), 0, stream>>>(Qb, WprojT, bproj, out);
}